// Round 13
// baseline (151.293 us; speedup 1.0000x reference)
//
#include <hip/hip_runtime.h>

#define RANK  32
#define DIM   128
#define TROWS 64   // rows per wave-task = 4 MFMA tile-rows

// Round-13: operand-swapped MFMA for float4 stores. Round 12 (130.4us) paid
// 128 scalar global_store_dword per task (C layout scatters a lane's 4 acc
// regs across 4 rows). The A- and B-fragment layouts of 16x16x32 are
// symmetric (m|n = l&15, same k-map — HW-verified by round 12 passing), so
// mfma(bfrag, af, 0) computes (W1g*W2)^T with the SAME fragment data: lane l
// reg rr then holds out[16tr+mn][16tc+4q+rr] — 4 CONTIGUOUS dims of one row
// -> one aligned float4 store per tile. 128 stores/task -> 32; 256B covered
// per store instruction -> 1KB. Everything else identical to round 12.
// Layouts (m89/m162-verified): A[m][k],B[k][n]: lane l elem e <-> m|n=l&15,
// k=4*(l>>4)+(e&3)+16*(e>>2). C: row=(l>>4)*4+reg, col=l&15.

typedef __attribute__((ext_vector_type(8))) short bf16x8;
typedef __attribute__((ext_vector_type(4))) float f32x4;

static __device__ __forceinline__ short f2bf(float f) {
  unsigned u = __float_as_uint(f);
  return (short)((u + 0x7FFFu + ((u >> 16) & 1u)) >> 16);  // RNE
}

__global__ __launch_bounds__(256)
__attribute__((amdgpu_waves_per_eu(4, 4)))
void lowrank_emb_kernel(
    const int* __restrict__ idx,
    const float* __restrict__ W1,
    const float* __restrict__ W2,
    float* __restrict__ out,
    int n_rows)
{
  const int lane       = threadIdx.x & 63;
  const int globalWave = blockIdx.x * 4 + (threadIdx.x >> 6);
  const int totalWaves = gridDim.x * 4;

  const int q   = lane >> 4;   // k-quad selector (0..3)
  const int mn  = lane & 15;   // row-of-A / col-of-B within tile
  const int nTasks  = (n_rows + TROWS - 1) / TROWS;
  const int lastIdx = n_rows - 1;

  // W2 fragments (used as the A operand after the swap): lane l elem e holds
  // bf16(W2[4q+(e&3)+16*(e>>2)][16t+mn]). 32 VGPRs, pinned resident.
  bf16x8 bfrag[8];
#pragma unroll
  for (int t = 0; t < 8; ++t) {
    bf16x8 v;
#pragma unroll
    for (int e = 0; e < 8; ++e) {
      const int k = 4 * q + (e & 3) + 16 * (e >> 2);
      v[e] = f2bf(W2[k * DIM + 16 * t + mn]);
    }
    bfrag[t] = v;
  }
#pragma unroll
  for (int t = 0; t < 8; ++t) asm("" : "+v"(bfrag[t]));

  for (int task = globalWave; task < nTasks; task += totalWaves) {
    const int rowBase = task * TROWS;

    // Coalesced idx load: lane l carries idx[rowBase+l].
    const int r = rowBase + lane;
    const int iv = idx[r < n_rows ? r : lastIdx];

    // A gather straight from global: tile-row tr needs W1 row 16tr+mn,
    // k-chunks [4q,4q+4) and [16+4q,+4). 8 independent 16B loads in flight;
    // each W1 row fetched exactly once (4 lanes x 2 chunks).
    float4 alo[4], ahi[4];
#pragma unroll
    for (int tr = 0; tr < 4; ++tr) {
      const int e = __shfl(iv, tr * 16 + mn, 64);
      const float* rp = W1 + (size_t)e * RANK + 4 * q;
      alo[tr] = *reinterpret_cast<const float4*>(rp);
      ahi[tr] = *reinterpret_cast<const float4*>(rp + 16);
    }

    // Convert to fragments (elems 0-3: k=4q+0..3; 4-7: k=16+4q+0..3).
    bf16x8 af[4];
#pragma unroll
    for (int tr = 0; tr < 4; ++tr) {
      bf16x8 v;
      v[0] = f2bf(alo[tr].x); v[1] = f2bf(alo[tr].y);
      v[2] = f2bf(alo[tr].z); v[3] = f2bf(alo[tr].w);
      v[4] = f2bf(ahi[tr].x); v[5] = f2bf(ahi[tr].y);
      v[6] = f2bf(ahi[tr].z); v[7] = f2bf(ahi[tr].w);
      af[tr] = v;
    }

    // Swapped compute: acc[tc] = W2tile(tc)^T x W1rows(tr)^T = out^T tile.
    // Lane l reg rr = out[rowBase+16tr+mn][16tc+4q+rr] -> float4 store.
    const bool full = (rowBase + TROWS) <= n_rows;
#pragma unroll
    for (int tr = 0; tr < 4; ++tr) {
      f32x4 acc[8];
#pragma unroll
      for (int tc = 0; tc < 8; ++tc)
        acc[tc] = __builtin_amdgcn_mfma_f32_16x16x32_bf16(
            bfrag[tc], af[tr], (f32x4){0.f, 0.f, 0.f, 0.f}, 0, 0, 0);

      const int orow = rowBase + tr * 16 + mn;
      float* op = out + (size_t)orow * DIM + 4 * q;
      if (full || orow < n_rows) {
#pragma unroll
        for (int tc = 0; tc < 8; ++tc)
          *reinterpret_cast<float4*>(op + 16 * tc) =
              make_float4(acc[tc][0], acc[tc][1], acc[tc][2], acc[tc][3]);
      }
    }
  }
}

extern "C" void kernel_launch(void* const* d_in, const int* in_sizes, int n_in,
                              void* d_out, int out_size, void* d_ws, size_t ws_size,
                              hipStream_t stream) {
  const int*   idx = (const int*)d_in[0];   // [4096*200]
  const float* W1  = (const float*)d_in[1]; // [1e6, 32]
  const float* W2  = (const float*)d_in[2]; // [32, 128]
  float*       out = (float*)d_out;         // [4096*200, 128]
  const int n_rows = in_sizes[0];

  const int threads = 256;   // 4 waves/block
  const int blocks  = 1024;  // 4 blocks/CU resident at the 128-VGPR class
  hipLaunchKernelGGL(lowrank_emb_kernel, dim3(blocks), dim3(threads), 0, stream,
                     idx, W1, W2, out, n_rows);
}

// Round 14
// 126.962 us; speedup vs baseline: 1.1916x; 1.1916x over previous
//
#include <hip/hip_runtime.h>

#define RANK  32
#define DIM   128
#define TROWS 64   // rows per wave-task = 4 MFMA tile-rows

// Round-14 = round 12 (130.4us, proven) + 2-task software pipeline.
// Round-13 lesson: stores produce identical 64B-segment counts either way —
// store shape is NOT the lever; reverted to round-12's scalar-store path.
// The real slack is the per-task serial chain (idx ~700cy -> gather ~900cy
// -> compute ~800cy, mostly exposed). Fixes: (1) grid sized for EXACTLY two
// tasks per wave (12800 tasks / 6400 waves) — no grid-stride tail imbalance;
// (2) both tasks' idx loads issue together at wave start; (3) task-1's
// gathers issue BEFORE task-0's compute (right after task-0's cvt frees the
// load regs), so the second gather latency hides fully under task-0's
// MFMA+stores. Register peak ~120 of the 128-VGPR class (waves_per_eu(4,4),
// the only proven-clean directive: rounds 7/11/12).
// Layouts (m89/m162-verified, HW-confirmed by rounds 12/13 passing):
// A[m][k],B[k][n]: lane l elem e <-> m|n=l&15, k=4*(l>>4)+(e&3)+16*(e>>2).
// C: row=(l>>4)*4+reg, col=l&15.

typedef __attribute__((ext_vector_type(8))) short bf16x8;
typedef __attribute__((ext_vector_type(4))) float f32x4;

static __device__ __forceinline__ short f2bf(float f) {
  unsigned u = __float_as_uint(f);
  return (short)((u + 0x7FFFu + ((u >> 16) & 1u)) >> 16);  // RNE
}

__global__ __launch_bounds__(256)
__attribute__((amdgpu_waves_per_eu(4, 4)))
void lowrank_emb_kernel(
    const int* __restrict__ idx,
    const float* __restrict__ W1,
    const float* __restrict__ W2,
    float* __restrict__ out,
    int n_rows)
{
  const int lane       = threadIdx.x & 63;
  const int globalWave = blockIdx.x * 4 + (threadIdx.x >> 6);

  const int q   = lane >> 4;   // k-quad selector (0..3)
  const int mn  = lane & 15;   // row-of-A / col-of-B within tile
  const int nTasks  = (n_rows + TROWS - 1) / TROWS;
  const int lastIdx = n_rows - 1;

  const int t0 = globalWave * 2;
  const int t1 = t0 + 1;
  if (t0 >= nTasks) return;
  const bool has1 = (t1 < nTasks);

  // W2 B-fragments: lane l elem e holds bf16(W2[4q+(e&3)+16*(e>>2)][16t+mn]).
  // 32 VGPRs, pinned resident (round-1 lesson).
  bf16x8 bfrag[8];
#pragma unroll
  for (int t = 0; t < 8; ++t) {
    bf16x8 v;
#pragma unroll
    for (int e = 0; e < 8; ++e) {
      const int k = 4 * q + (e & 3) + 16 * (e >> 2);
      v[e] = f2bf(W2[k * DIM + 16 * t + mn]);
    }
    bfrag[t] = v;
  }
#pragma unroll
  for (int t = 0; t < 8; ++t) asm("" : "+v"(bfrag[t]));

  // (1) Both tasks' indices, issued together (coalesced; latencies overlap).
  int iv0, iv1;
  {
    const int r0 = t0 * TROWS + lane;
    iv0 = idx[r0 < n_rows ? r0 : lastIdx];
    const int r1 = t1 * TROWS + lane;
    iv1 = idx[(has1 && r1 < n_rows) ? r1 : lastIdx];
  }

  // (2) Task-0 gathers: tile-row tr needs W1 row 16tr+mn, k-chunks [4q,+4)
  // and [16+4q,+4). 8 independent 16B loads; each row fetched exactly once.
  float4 alo[4], ahi[4];
#pragma unroll
  for (int tr = 0; tr < 4; ++tr) {
    const int e = __shfl(iv0, tr * 16 + mn, 64);
    const float* rp = W1 + (size_t)e * RANK + 4 * q;
    alo[tr] = *reinterpret_cast<const float4*>(rp);
    ahi[tr] = *reinterpret_cast<const float4*>(rp + 16);
  }

  // (3) Convert task-0 to fragments, freeing alo/ahi for task-1's loads.
  bf16x8 af0[4];
#pragma unroll
  for (int tr = 0; tr < 4; ++tr) {
    bf16x8 v;
    v[0] = f2bf(alo[tr].x); v[1] = f2bf(alo[tr].y);
    v[2] = f2bf(alo[tr].z); v[3] = f2bf(alo[tr].w);
    v[4] = f2bf(ahi[tr].x); v[5] = f2bf(ahi[tr].y);
    v[6] = f2bf(ahi[tr].z); v[7] = f2bf(ahi[tr].w);
    af0[tr] = v;
  }

  // (4) Task-1 gathers issue NOW — they fly during task-0's compute+store.
  if (has1) {
#pragma unroll
    for (int tr = 0; tr < 4; ++tr) {
      const int e = __shfl(iv1, tr * 16 + mn, 64);
      const float* rp = W1 + (size_t)e * RANK + 4 * q;
      alo[tr] = *reinterpret_cast<const float4*>(rp);
      ahi[tr] = *reinterpret_cast<const float4*>(rp + 16);
    }
  }

  // (5) Task-0 compute + store (round-12 proven path: scalar stores,
  // C layout row=(l>>4)*4+reg, col=l&15).
  {
    const int rowBase = t0 * TROWS;
    const bool full = (rowBase + TROWS) <= n_rows;
#pragma unroll
    for (int tr = 0; tr < 4; ++tr) {
      f32x4 acc[8];
#pragma unroll
      for (int tc = 0; tc < 8; ++tc)
        acc[tc] = __builtin_amdgcn_mfma_f32_16x16x32_bf16(
            af0[tr], bfrag[tc], (f32x4){0.f, 0.f, 0.f, 0.f}, 0, 0, 0);

      const int rb = rowBase + tr * 16 + q * 4;
#pragma unroll
      for (int rr = 0; rr < 4; ++rr) {
        if (full || (rb + rr) < n_rows) {
          float* op = out + (size_t)(rb + rr) * DIM + mn;
#pragma unroll
          for (int tc = 0; tc < 8; ++tc) op[16 * tc] = acc[tc][rr];
        }
      }
    }
  }

  // (6) Task-1 convert + compute + store (loads long since landed).
  if (has1) {
    bf16x8 af1[4];
#pragma unroll
    for (int tr = 0; tr < 4; ++tr) {
      bf16x8 v;
      v[0] = f2bf(alo[tr].x); v[1] = f2bf(alo[tr].y);
      v[2] = f2bf(alo[tr].z); v[3] = f2bf(alo[tr].w);
      v[4] = f2bf(ahi[tr].x); v[5] = f2bf(ahi[tr].y);
      v[6] = f2bf(ahi[tr].z); v[7] = f2bf(ahi[tr].w);
      af1[tr] = v;
    }
    const int rowBase = t1 * TROWS;
    const bool full = (rowBase + TROWS) <= n_rows;
#pragma unroll
    for (int tr = 0; tr < 4; ++tr) {
      f32x4 acc[8];
#pragma unroll
      for (int tc = 0; tc < 8; ++tc)
        acc[tc] = __builtin_amdgcn_mfma_f32_16x16x32_bf16(
            af1[tr], bfrag[tc], (f32x4){0.f, 0.f, 0.f, 0.f}, 0, 0, 0);

      const int rb = rowBase + tr * 16 + q * 4;
#pragma unroll
      for (int rr = 0; rr < 4; ++rr) {
        if (full || (rb + rr) < n_rows) {
          float* op = out + (size_t)(rb + rr) * DIM + mn;
#pragma unroll
          for (int tc = 0; tc < 8; ++tc) op[16 * tc] = acc[tc][rr];
        }
      }
    }
  }
}

extern "C" void kernel_launch(void* const* d_in, const int* in_sizes, int n_in,
                              void* d_out, int out_size, void* d_ws, size_t ws_size,
                              hipStream_t stream) {
  const int*   idx = (const int*)d_in[0];   // [4096*200]
  const float* W1  = (const float*)d_in[1]; // [1e6, 32]
  const float* W2  = (const float*)d_in[2]; // [32, 128]
  float*       out = (float*)d_out;         // [4096*200, 128]
  const int n_rows = in_sizes[0];

  // Exactly 2 tasks per wave: nTasks=12800 -> 6400 waves -> 1600 blocks.
  const int nTasks  = (n_rows + TROWS - 1) / TROWS;
  const int nWaves  = (nTasks + 1) / 2;
  const int blocks  = (nWaves + 3) / 4;
  hipLaunchKernelGGL(lowrank_emb_kernel, dim3(blocks), dim3(256), 0, stream,
                     idx, W1, W2, out, n_rows);
}

// Round 15
// 126.060 us; speedup vs baseline: 1.2002x; 1.0072x over previous
//
#include <hip/hip_runtime.h>

#define RANK  32
#define DIM   128
#define TROWS 64   // rows per wave-task = 4 MFMA tile-rows

// Round-15 = round 14 (127.0us) rolled into a persistent steady-state loop.
// Round-14 residuals: (a) per-wave prologue (idx ~700cy + first gather
// ~900cy naked) amortized over only 2 tasks; (b) 1600 blocks / 1024
// resident slots = 1.56 dispatch rounds, final round at ~56% occupancy.
// Fix: exactly 1024 blocks (full residency, persistent), each wave loops
// ~3.1 tasks with the rolling overlap: cvt(t) -> issue gathers(t+1) ->
// prefetch idx(t+2) -> compute+store(t). Live set identical to round 14
// (~120 VGPRs, inside the proven-clean waves_per_eu(4,4) 128 class).
// Layouts (m89/m162-verified, HW-confirmed rounds 12-14):
// A[m][k],B[k][n]: lane l elem e <-> m|n=l&15, k=4*(l>>4)+(e&3)+16*(e>>2).
// C: row=(l>>4)*4+reg, col=l&15.

typedef __attribute__((ext_vector_type(8))) short bf16x8;
typedef __attribute__((ext_vector_type(4))) float f32x4;

static __device__ __forceinline__ short f2bf(float f) {
  unsigned u = __float_as_uint(f);
  return (short)((u + 0x7FFFu + ((u >> 16) & 1u)) >> 16);  // RNE
}

__global__ __launch_bounds__(256)
__attribute__((amdgpu_waves_per_eu(4, 4)))
void lowrank_emb_kernel(
    const int* __restrict__ idx,
    const float* __restrict__ W1,
    const float* __restrict__ W2,
    float* __restrict__ out,
    int n_rows)
{
  const int lane       = threadIdx.x & 63;
  const int globalWave = blockIdx.x * 4 + (threadIdx.x >> 6);
  const int totalWaves = gridDim.x * 4;

  const int q   = lane >> 4;   // k-quad selector (0..3)
  const int mn  = lane & 15;   // row-of-A / col-of-B within tile
  const int nTasks  = (n_rows + TROWS - 1) / TROWS;
  const int lastIdx = n_rows - 1;

  int t = globalWave;
  if (t >= nTasks) return;

  // W2 B-fragments: lane l elem e holds bf16(W2[4q+(e&3)+16*(e>>2)][16t+mn]).
  // 32 VGPRs, pinned resident (round-1 lesson).
  bf16x8 bfrag[8];
#pragma unroll
  for (int tt = 0; tt < 8; ++tt) {
    bf16x8 v;
#pragma unroll
    for (int e = 0; e < 8; ++e) {
      const int k = 4 * q + (e & 3) + 16 * (e >> 2);
      v[e] = f2bf(W2[k * DIM + 16 * tt + mn]);
    }
    bfrag[tt] = v;
  }
#pragma unroll
  for (int tt = 0; tt < 8; ++tt) asm("" : "+v"(bfrag[tt]));

  // Prologue: idx + gathers for task t; idx prefetch for t+stride.
  auto gather = [&](int iv, float4* lo, float4* hi) {
    // Tile-row tr needs W1 row 16tr+mn, k-chunks [4q,+4) and [16+4q,+4).
    // 8 independent 16B loads; each W1 row fetched exactly once per task.
#pragma unroll
    for (int tr = 0; tr < 4; ++tr) {
      const int e = __shfl(iv, tr * 16 + mn, 64);
      const float* rp = W1 + (size_t)e * RANK + 4 * q;
      lo[tr] = *reinterpret_cast<const float4*>(rp);
      hi[tr] = *reinterpret_cast<const float4*>(rp + 16);
    }
  };

  float4 alo[4], ahi[4];
  {
    const int r = t * TROWS + lane;
    const int iv0 = idx[r < n_rows ? r : lastIdx];
    gather(iv0, alo, ahi);
  }
  int ivNext;
  {
    const int tn = t + totalWaves;
    const int r  = tn * TROWS + lane;
    ivNext = idx[(tn < nTasks && r < n_rows) ? r : lastIdx];
  }

  while (true) {
    // (1) Convert current task's gather (compiler waits vmcnt here) to
    // fragments, freeing alo/ahi registers for the next task's loads.
    bf16x8 af[4];
#pragma unroll
    for (int tr = 0; tr < 4; ++tr) {
      bf16x8 v;
      v[0] = f2bf(alo[tr].x); v[1] = f2bf(alo[tr].y);
      v[2] = f2bf(alo[tr].z); v[3] = f2bf(alo[tr].w);
      v[4] = f2bf(ahi[tr].x); v[5] = f2bf(ahi[tr].y);
      v[6] = f2bf(ahi[tr].z); v[7] = f2bf(ahi[tr].w);
      af[tr] = v;
    }

    // (2) Issue NEXT task's gathers now — they fly under this task's
    // MFMA + stores (round-14's proven overlap, now in steady state).
    const int tn = t + totalWaves;
    if (tn < nTasks) gather(ivNext, alo, ahi);

    // (3) Prefetch idx two tasks ahead (lands long before its gather).
    {
      const int t2 = tn + totalWaves;
      const int r  = t2 * TROWS + lane;
      ivNext = idx[(t2 < nTasks && r < n_rows) ? r : lastIdx];
    }

    // (4) Compute + store current task (round-12 proven scalar-store path).
    const int rowBase = t * TROWS;
    const bool full = (rowBase + TROWS) <= n_rows;
#pragma unroll
    for (int tr = 0; tr < 4; ++tr) {
      f32x4 acc[8];
#pragma unroll
      for (int tc = 0; tc < 8; ++tc)
        acc[tc] = __builtin_amdgcn_mfma_f32_16x16x32_bf16(
            af[tr], bfrag[tc], (f32x4){0.f, 0.f, 0.f, 0.f}, 0, 0, 0);

      const int rb = rowBase + tr * 16 + q * 4;  // C: row=(l>>4)*4+reg
#pragma unroll
      for (int rr = 0; rr < 4; ++rr) {
        if (full || (rb + rr) < n_rows) {
          float* op = out + (size_t)(rb + rr) * DIM + mn;
#pragma unroll
          for (int tc = 0; tc < 8; ++tc) op[16 * tc] = acc[tc][rr];
        }
      }
    }

    if (tn >= nTasks) break;
    t = tn;
  }
}

extern "C" void kernel_launch(void* const* d_in, const int* in_sizes, int n_in,
                              void* d_out, int out_size, void* d_ws, size_t ws_size,
                              hipStream_t stream) {
  const int*   idx = (const int*)d_in[0];   // [4096*200]
  const float* W1  = (const float*)d_in[1]; // [1e6, 32]
  const float* W2  = (const float*)d_in[2]; // [32, 128]
  float*       out = (float*)d_out;         // [4096*200, 128]
  const int n_rows = in_sizes[0];

  const int threads = 256;   // 4 waves/block
  const int blocks  = 1024;  // exactly resident (4 blocks/CU); persistent loop
  hipLaunchKernelGGL(lowrank_emb_kernel, dim3(blocks), dim3(threads), 0, stream,
                     idx, W1, W2, out, n_rows);
}